// Round 18
// baseline (85.931 us; speedup 1.0000x reference)
//
#include <hip/hip_runtime.h>
#include <hip/hip_bf16.h>
#include <stdint.h>

#define NROWS 4096
#define DIMS  2048
#define BM    128             // tile 128x128
#define BKB   64              // K-tile = 64 int8 = 64 B rows
#define NTILES (DIMS / BKB)   // 32
#define NTB   (NROWS / BM)    // 32 -> 1024 blocks
#define MARGIN_F 0.3f

typedef __attribute__((ext_vector_type(4)))  int i32x4;
typedef __attribute__((ext_vector_type(16))) int i32x16;

__device__ inline void atomicMaxF(float* addr, float v) {
  if (v >= 0.f) atomicMax((int*)addr, __float_as_int(v));
  else          atomicMin((unsigned int*)addr, __float_as_uint(v));
}
__device__ inline void atomicMinF(float* addr, float v) {
  if (v >= 0.f) atomicMin((int*)addr, __float_as_int(v));
  else          atomicMax((unsigned int*)addr, __float_as_uint(v));
}

__device__ inline void load_lds16(const void* g, void* l) {
  __builtin_amdgcn_global_load_lds(
      (const __attribute__((address_space(1))) void*)(g),
      (__attribute__((address_space(3))) void*)(l), 16, 0, 0);
}

// ------- normalize + per-row int8 quantization (q = rint(x*127/amax)) -------
__global__ __launch_bounds__(256) void norm_kernel(const float* __restrict__ in,
                                                   char* __restrict__ l2q,
                                                   float* __restrict__ recip,
                                                   float* __restrict__ dap,
                                                   float* __restrict__ dan) {
  int row = blockIdx.x;
  int t = threadIdx.x;
  const float4* rin = (const float4*)(in + (size_t)row * DIMS);
  float4 v0 = rin[t];
  float4 v1 = rin[t + 256];
  float ss = v0.x*v0.x + v0.y*v0.y + v0.z*v0.z + v0.w*v0.w
           + v1.x*v1.x + v1.y*v1.y + v1.z*v1.z + v1.w*v1.w;
  float am = fmaxf(fmaxf(fmaxf(fabsf(v0.x), fabsf(v0.y)), fmaxf(fabsf(v0.z), fabsf(v0.w))),
                   fmaxf(fmaxf(fabsf(v1.x), fabsf(v1.y)), fmaxf(fabsf(v1.z), fabsf(v1.w))));
  #pragma unroll
  for (int s = 1; s < 64; s <<= 1) {
    ss += __shfl_xor(ss, s);
    am = fmaxf(am, __shfl_xor(am, s));
  }
  __shared__ float wsum[4], wmax[4];
  if ((t & 63) == 0) { wsum[t >> 6] = ss; wmax[t >> 6] = am; }
  __syncthreads();
  float tot = wsum[0] + wsum[1] + wsum[2] + wsum[3];
  float amax = fmaxf(fmaxf(wmax[0], wmax[1]), fmaxf(wmax[2], wmax[3]));
  float rn = 1.0f / sqrtf(tot);
  float qs = 127.0f / amax;
  int q0 = (int)rintf(v0.x * qs), q1 = (int)rintf(v0.y * qs);
  int q2 = (int)rintf(v0.z * qs), q3 = (int)rintf(v0.w * qs);
  int q4 = (int)rintf(v1.x * qs), q5 = (int)rintf(v1.y * qs);
  int q6 = (int)rintf(v1.z * qs), q7 = (int)rintf(v1.w * qs);
  int p0 = (q0 & 255) | ((q1 & 255) << 8) | ((q2 & 255) << 16) | (q3 << 24);
  int p1 = (q4 & 255) | ((q5 & 255) << 8) | ((q6 & 255) << 16) | (q7 << 24);
  int* orow = (int*)(l2q + (size_t)row * DIMS);
  orow[t] = p0;
  orow[t + 256] = p1;
  if (t == 0) {
    recip[row] = amax * rn / 127.0f;
    dap[row] = -__builtin_inff();
    dan[row] = __builtin_inff();
  }
}

// ---------------- fused int8 GEMM (acc = Q . Q^T) + masked row max/min ----------------
// r17 winning skeleton (128x128 tile, 4 waves 2x2 of 64x64, 4 blocks/CU)
// with: (1) mfma_i32_32x32x32_i8 (4404-TOPS ceiling vs 3944; 8 MFMA/wave/
// K-tile vs 16) -- b128 reads process in 16-lane quarters, so the verified
// (row>>1)&3 chunk swizzle stays 2-way/free for the 32-row fragment reads;
// (2) double-buffered LDS (2 x 16 KB, still 4 blocks/CU): stage tile t+1,
// compute tile t, ONE __syncthreads per tile (its vmcnt(0) drain waits
// loads issued a full compute phase earlier).
// C/D layout (32x32, m74/m101): col = lane&31, row = (reg&3)+8*(reg>>2)
// +4*(lane>>5); halves h=0/1 own disjoint rows; row-reduce = 5 shfl steps.
__global__ __launch_bounds__(256, 4) void gemm_reduce_kernel(
    const char* __restrict__ l2q, const int* __restrict__ tgt,
    const float* __restrict__ recip,
    float* __restrict__ dap, float* __restrict__ dan) {
  __shared__ __attribute__((aligned(16))) char ldsbuf[2][16384];  // per buf: A 8K + B 8K

  // XCD-chunked bijective swizzle (1024 blocks, 8 XCDs -> 128 contiguous per XCD)
  int c = blockIdx.x;
  int swz = (c & 7) * 128 + (c >> 3);
  int bi = swz >> 5, bj = swz & 31;

  int tid = threadIdx.x;
  int lane = tid & 63, w = tid >> 6;
  int wr = w >> 1;        // 0..1  (M half: 64 rows)
  int nc = w & 1;         // 0..1  (N half: 64 cols)
  int l31 = lane & 31, h = lane >> 5;

  i32x16 acc[2][2];
  #pragma unroll
  for (int mb = 0; mb < 2; mb++)
    #pragma unroll
    for (int nb = 0; nb < 2; nb++)
      #pragma unroll
      for (int r = 0; r < 16; r++) acc[mb][nb][r] = 0;

  // --- staging source (r17-identical): thread tid covers rows tid>>2 / +64,
  //     data chunk q = (tid&3) ^ ((row>>1)&3); coalesced 64 B per 4 threads ---
  int srow = tid >> 2;
  int qq = (tid & 3) ^ ((tid >> 3) & 3);
  const char* gA = l2q + ((size_t)(bi * BM + srow)) * DIMS + qq * 16;
  const char* gB = l2q + ((size_t)(bj * BM + srow)) * DIMS + qq * 16;

  // --- fragment read addresses (32x32 operand: lane l -> row l31, chunk
  //     c = ks*2 + h; slot = c ^ ((row>>1)&3); within-quarter rows 0..15
  //     spread 2-way over banks = free) ---
  int swzl = (l31 >> 1) & 3;
  int rowA = wr * 64 + l31;          // + mb*32
  int rowB = nc * 64 + l31;          // + nb*32
  // addr(row, ks) = row*64 + ((ks*2+h)^swzl)*16 ; B region at +8192

  #define STAGE(T, P)                                                         \
    do {                                                                      \
      load_lds16(gA + (size_t)(T) * BKB, &ldsbuf[P][w * 1024]);               \
      load_lds16(gA + (size_t)64 * DIMS + (size_t)(T) * BKB,                  \
                 &ldsbuf[P][4096 + w * 1024]);                                \
      load_lds16(gB + (size_t)(T) * BKB, &ldsbuf[P][8192 + w * 1024]);        \
      load_lds16(gB + (size_t)64 * DIMS + (size_t)(T) * BKB,                  \
                 &ldsbuf[P][12288 + w * 1024]);                               \
    } while (0)

  #define COMPUTE(P)                                                          \
    do {                                                                      \
      _Pragma("unroll")                                                       \
      for (int ks = 0; ks < 2; ++ks) {                                        \
        int slot = ((ks * 2 + h) ^ swzl) * 16;                                \
        i32x4 aF[2], bF[2];                                                   \
        _Pragma("unroll")                                                     \
        for (int mb = 0; mb < 2; mb++)                                        \
          aF[mb] = *(const i32x4*)&ldsbuf[P][(rowA + mb * 32) * 64 + slot];   \
        _Pragma("unroll")                                                     \
        for (int nb = 0; nb < 2; nb++)                                        \
          bF[nb] = *(const i32x4*)&ldsbuf[P][8192 + (rowB + nb * 32) * 64 + slot]; \
        _Pragma("unroll")                                                     \
        for (int mb = 0; mb < 2; mb++)                                        \
          _Pragma("unroll")                                                   \
          for (int nb = 0; nb < 2; nb++)                                      \
            acc[mb][nb] = __builtin_amdgcn_mfma_i32_32x32x32_i8(              \
                aF[mb], bF[nb], acc[mb][nb], 0, 0, 0);                        \
      }                                                                       \
    } while (0)

  // prologue: stage tile 0 into buf 0, cold drain
  STAGE(0, 0);
  __syncthreads();

  int p = 0;
  #pragma unroll 1
  for (int kt = 0; kt < NTILES; ++kt) {
    if (kt + 1 < NTILES) STAGE(kt + 1, p ^ 1);   // lands during COMPUTE
    COMPUTE(p);
    __syncthreads();     // drains vmcnt (tile kt+1 staged) + closes buf reuse
    p ^= 1;
  }

  // ---- fused masked reduction (32x32 C/D layout) ----
  // acc[mb][nb][r]: row = bi*128 + wr*64 + mb*32 + (r&3)+8*(r>>2)+4*h
  //                 col = bj*128 + nc*64 + nb*32 + l31
  int tcol2[2];
  float tcr2[2];
  #pragma unroll
  for (int nb = 0; nb < 2; nb++) {
    int idx = bj * BM + nc * 64 + nb * 32 + l31;
    tcol2[nb] = tgt[idx];
    tcr2[nb] = recip[idx];
  }
  int rbase = bi * BM + wr * 64 + 4 * h;

  #pragma unroll
  for (int mb = 0; mb < 2; mb++) {
    #pragma unroll
    for (int r = 0; r < 16; r++) {
      int grow = rbase + mb * 32 + (r & 3) + 8 * (r >> 2);
      int trow = tgt[grow];
      float rrw = recip[grow];
      float ap = -__builtin_inff(), an = __builtin_inff();
      #pragma unroll
      for (int nb = 0; nb < 2; nb++) {
        float d = -(float)acc[mb][nb][r] * rrw * tcr2[nb];
        bool same = (trow == tcol2[nb]);
        ap = same ? fmaxf(ap, d) : ap;
        an = same ? an : fminf(an, d);
      }
      #pragma unroll
      for (int s = 1; s < 32; s <<= 1) {   // 5 steps, stays within 32-half
        ap = fmaxf(ap, __shfl_xor(ap, s));
        an = fminf(an, __shfl_xor(an, s));
      }
      if (l31 == 0) {
        atomicMaxF(&dap[grow], ap);
        atomicMinF(&dan[grow], an);
      }
    }
  }
  #undef STAGE
  #undef COMPUTE
}

// ---------------- final loss ----------------
__global__ __launch_bounds__(256) void loss_kernel(const float* __restrict__ dap,
                                                   const float* __restrict__ dan,
                                                   float* __restrict__ out) {
  int t = threadIdx.x;
  float s = 0.f;
  for (int i = t; i < NROWS; i += 256) {
    float v = dap[i] - dan[i] + MARGIN_F;
    s += v > 0.f ? v : 0.f;
  }
  #pragma unroll
  for (int sh = 1; sh < 64; sh <<= 1) s += __shfl_xor(s, sh);
  __shared__ float ws[4];
  if ((t & 63) == 0) ws[t >> 6] = s;
  __syncthreads();
  if (t == 0) out[0] = (ws[0] + ws[1] + ws[2] + ws[3]) * (1.0f / (float)NROWS);
}

extern "C" void kernel_launch(void* const* d_in, const int* in_sizes, int n_in,
                              void* d_out, int out_size, void* d_ws, size_t ws_size,
                              hipStream_t stream) {
  const float* inputs = (const float*)d_in[0];
  const int* targets = (const int*)d_in[1];
  char* l2q = (char*)d_ws;
  float* recip = (float*)((char*)d_ws + (size_t)NROWS * DIMS);
  float* dap = recip + NROWS;
  float* dan = dap + NROWS;
  float* out = (float*)d_out;

  hipLaunchKernelGGL(norm_kernel, dim3(NROWS), dim3(256), 0, stream,
                     inputs, l2q, recip, dap, dan);
  hipLaunchKernelGGL(gemm_reduce_kernel, dim3(NTB * NTB), dim3(256), 0, stream,
                     l2q, targets, recip, dap, dan);
  hipLaunchKernelGGL(loss_kernel, dim3(1), dim3(256), 0, stream, dap, dan, out);
}

// Round 19
// 68.786 us; speedup vs baseline: 1.2492x; 1.2492x over previous
//
#include <hip/hip_runtime.h>
#include <hip/hip_bf16.h>
#include <stdint.h>

#define NROWS 4096
#define DIMS  2048
#define BM    128             // tile 128x128
#define BKB   64              // K-tile = 64 int8 = 64 B rows
#define NTILES (DIMS / BKB)   // 32
#define NTB   (NROWS / BM)    // 32 -> 1024 blocks
#define MARGIN_F 0.3f

typedef __attribute__((ext_vector_type(4))) int   i32x4;
typedef __attribute__((ext_vector_type(4))) float f32x4;

__device__ inline void atomicMaxF(float* addr, float v) {
  if (v >= 0.f) atomicMax((int*)addr, __float_as_int(v));
  else          atomicMin((unsigned int*)addr, __float_as_uint(v));
}
__device__ inline void atomicMinF(float* addr, float v) {
  if (v >= 0.f) atomicMin((int*)addr, __float_as_int(v));
  else          atomicMax((unsigned int*)addr, __float_as_uint(v));
}

__device__ inline void load_lds16(const void* g, void* l) {
  __builtin_amdgcn_global_load_lds(
      (const __attribute__((address_space(1))) void*)(g),
      (__attribute__((address_space(3))) void*)(l), 16, 0, 0);
}

// ------- normalize + per-row int8 quantization (q = rint(x*127/amax)) -------
__global__ __launch_bounds__(256) void norm_kernel(const float* __restrict__ in,
                                                   char* __restrict__ l2q,
                                                   float* __restrict__ recip,
                                                   float* __restrict__ dap,
                                                   float* __restrict__ dan) {
  int row = blockIdx.x;
  int t = threadIdx.x;
  const float4* rin = (const float4*)(in + (size_t)row * DIMS);
  float4 v0 = rin[t];
  float4 v1 = rin[t + 256];
  float ss = v0.x*v0.x + v0.y*v0.y + v0.z*v0.z + v0.w*v0.w
           + v1.x*v1.x + v1.y*v1.y + v1.z*v1.z + v1.w*v1.w;
  float am = fmaxf(fmaxf(fmaxf(fabsf(v0.x), fabsf(v0.y)), fmaxf(fabsf(v0.z), fabsf(v0.w))),
                   fmaxf(fmaxf(fabsf(v1.x), fabsf(v1.y)), fmaxf(fabsf(v1.z), fabsf(v1.w))));
  #pragma unroll
  for (int s = 1; s < 64; s <<= 1) {
    ss += __shfl_xor(ss, s);
    am = fmaxf(am, __shfl_xor(am, s));
  }
  __shared__ float wsum[4], wmax[4];
  if ((t & 63) == 0) { wsum[t >> 6] = ss; wmax[t >> 6] = am; }
  __syncthreads();
  float tot = wsum[0] + wsum[1] + wsum[2] + wsum[3];
  float amax = fmaxf(fmaxf(wmax[0], wmax[1]), fmaxf(wmax[2], wmax[3]));
  float rn = 1.0f / sqrtf(tot);
  float qs = 127.0f / amax;
  int q0 = (int)rintf(v0.x * qs), q1 = (int)rintf(v0.y * qs);
  int q2 = (int)rintf(v0.z * qs), q3 = (int)rintf(v0.w * qs);
  int q4 = (int)rintf(v1.x * qs), q5 = (int)rintf(v1.y * qs);
  int q6 = (int)rintf(v1.z * qs), q7 = (int)rintf(v1.w * qs);
  int p0 = (q0 & 255) | ((q1 & 255) << 8) | ((q2 & 255) << 16) | (q3 << 24);
  int p1 = (q4 & 255) | ((q5 & 255) << 8) | ((q6 & 255) << 16) | (q7 << 24);
  int* orow = (int*)(l2q + (size_t)row * DIMS);
  orow[t] = p0;
  orow[t + 256] = p1;
  if (t == 0) {
    recip[row] = amax * rn / 127.0f;
    dap[row] = -__builtin_inff();
    dan[row] = __builtin_inff();
  }
}

// ---------------- fused int8 GEMM (acc = Q . Q^T) + masked row max/min ----------------
// r17 winning skeleton UNCHANGED (128x128 tile, 4 waves 2x2 of 64x64,
// mfma_i32_16x16x64_i8, 4 blocks/CU, verified 0-conflict addressing) with
// ONE isolated change: double-buffered LDS (2 x 16 KB, still 4 blocks/CU at
// 128 KB) and ONE __syncthreads per K-tile. STAGE(t+1) is issued BEFORE
// COMPUTE(t), so the sync's vmcnt(0) drain waits loads that had a full
// compute phase to land; barrier count halves (2 -> 1 per tile). This
// targets the ~460 cy/tile sync/drain slack in r17's 979-cy budget.
// (r18's -39% is attributed to its 32x32 read pattern's 4cy/inst bank
// conflict -- quarters 0&1 shared bank patterns; this kernel restores the
// proven conflict-free 16-row-quarter reads.)
__global__ __launch_bounds__(256, 4) void gemm_reduce_kernel(
    const char* __restrict__ l2q, const int* __restrict__ tgt,
    const float* __restrict__ recip,
    float* __restrict__ dap, float* __restrict__ dan) {
  __shared__ __attribute__((aligned(16))) char ldsbuf[2][16384];  // per buf: A 8K + B 8K

  // XCD-chunked bijective swizzle (1024 blocks, 8 XCDs -> 128 contiguous per XCD)
  int c = blockIdx.x;
  int swz = (c & 7) * 128 + (c >> 3);
  int bi = swz >> 5, bj = swz & 31;

  int tid = threadIdx.x;
  int lane = tid & 63, w = tid >> 6;
  int wr = w >> 1;        // 0..1  (M half: 64 rows)
  int nc = w & 1;         // 0..1  (N half: 64 cols)
  int laneq = lane & 15, g = lane >> 4;

  i32x4 acc[4][4];
  #pragma unroll
  for (int m = 0; m < 4; m++)
    #pragma unroll
    for (int n = 0; n < 4; n++) acc[m][n] = (i32x4){0, 0, 0, 0};

  // --- staging source (r17-identical): thread tid covers rows tid>>2 / +64,
  //     data chunk q = (tid&3) ^ ((row>>1)&3); coalesced 64 B per 4 threads ---
  int srow = tid >> 2;
  int qq = (tid & 3) ^ ((tid >> 3) & 3);
  const char* gA = l2q + ((size_t)(bi * BM + srow)) * DIMS + qq * 16;
  const char* gB = l2q + ((size_t)(bj * BM + srow)) * DIMS + qq * 16;

  // --- fragment read offsets (r17-identical; verified 0 conflicts) ---
  int fcB = (g ^ ((laneq >> 1) & 3)) * 16;           // swizzled 16B chunk slot
  int aOffB = (wr * 64 + laneq) * 64 + fcB;
  int bOffB = 8192 + (nc * 64 + laneq) * 64 + fcB;

  i32x4 aU[4], bR[4];

  #define STAGE(T, P)                                                         \
    do {                                                                      \
      load_lds16(gA + (size_t)(T) * BKB, &ldsbuf[P][w * 1024]);               \
      load_lds16(gA + (size_t)64 * DIMS + (size_t)(T) * BKB,                  \
                 &ldsbuf[P][4096 + w * 1024]);                                \
      load_lds16(gB + (size_t)(T) * BKB, &ldsbuf[P][8192 + w * 1024]);        \
      load_lds16(gB + (size_t)64 * DIMS + (size_t)(T) * BKB,                  \
                 &ldsbuf[P][12288 + w * 1024]);                               \
    } while (0)

  #define COMPUTE(P)                                                          \
    do {                                                                      \
      _Pragma("unroll")                                                       \
      for (int n = 0; n < 4; n++)                                             \
        bR[n] = *(const i32x4*)&ldsbuf[P][bOffB + n * 1024];                  \
      _Pragma("unroll")                                                       \
      for (int m = 0; m < 4; m++)                                             \
        aU[m] = *(const i32x4*)&ldsbuf[P][aOffB + m * 1024];                  \
      _Pragma("unroll")                                                       \
      for (int m = 0; m < 4; m++)                                             \
        _Pragma("unroll")                                                     \
        for (int n = 0; n < 4; n++)                                           \
          acc[m][n] = __builtin_amdgcn_mfma_i32_16x16x64_i8(aU[m], bR[n],     \
                                                            acc[m][n], 0, 0, 0); \
    } while (0)

  // prologue: stage tile 0 into buf 0, cold drain
  STAGE(0, 0);
  __syncthreads();

  int p = 0;
  #pragma unroll 1
  for (int kt = 0; kt < NTILES; ++kt) {
    if (kt + 1 < NTILES) STAGE(kt + 1, p ^ 1);   // lands during COMPUTE
    COMPUTE(p);
    __syncthreads();   // drains vmcnt (tile kt+1 staged) + closes buf reuse
    p ^= 1;
  }

  // ---- fused masked reduction (r17-identical, verified) ----
  // acc[m][n][r] = Gq[bi*128 + wr*64 + m*16 + g*4 + r]
  //                  [bj*128 + nc*64 + n*16 + laneq]
  int tcol[4];
  float tcr[4];
  #pragma unroll
  for (int n = 0; n < 4; n++) {
    int idx = bj * BM + nc * 64 + n * 16 + laneq;
    tcol[n] = tgt[idx];
    tcr[n] = recip[idx];
  }
  int rbase = bi * BM + wr * 64 + g * 4;

  #pragma unroll
  for (int m = 0; m < 4; m++) {
    #pragma unroll
    for (int r = 0; r < 4; r++) {
      int grow = rbase + m * 16 + r;
      int trow = tgt[grow];
      float rrw = recip[grow];
      float ap = -__builtin_inff(), an = __builtin_inff();
      #pragma unroll
      for (int n = 0; n < 4; n++) {
        float d = -(float)acc[m][n][r] * rrw * tcr[n];
        bool same = (trow == tcol[n]);
        ap = same ? fmaxf(ap, d) : ap;
        an = same ? an : fminf(an, d);
      }
      #pragma unroll
      for (int s = 1; s < 16; s <<= 1) {
        ap = fmaxf(ap, __shfl_xor(ap, s));
        an = fminf(an, __shfl_xor(an, s));
      }
      if (laneq == 0) {
        atomicMaxF(&dap[grow], ap);
        atomicMinF(&dan[grow], an);
      }
    }
  }
  #undef STAGE
  #undef COMPUTE
}

// ---------------- final loss ----------------
__global__ __launch_bounds__(256) void loss_kernel(const float* __restrict__ dap,
                                                   const float* __restrict__ dan,
                                                   float* __restrict__ out) {
  int t = threadIdx.x;
  float s = 0.f;
  for (int i = t; i < NROWS; i += 256) {
    float v = dap[i] - dan[i] + MARGIN_F;
    s += v > 0.f ? v : 0.f;
  }
  #pragma unroll
  for (int sh = 1; sh < 64; sh <<= 1) s += __shfl_xor(s, sh);
  __shared__ float ws[4];
  if ((t & 63) == 0) ws[t >> 6] = s;
  __syncthreads();
  if (t == 0) out[0] = (ws[0] + ws[1] + ws[2] + ws[3]) * (1.0f / (float)NROWS);
}

extern "C" void kernel_launch(void* const* d_in, const int* in_sizes, int n_in,
                              void* d_out, int out_size, void* d_ws, size_t ws_size,
                              hipStream_t stream) {
  const float* inputs = (const float*)d_in[0];
  const int* targets = (const int*)d_in[1];
  char* l2q = (char*)d_ws;
  float* recip = (float*)((char*)d_ws + (size_t)NROWS * DIMS);
  float* dap = recip + NROWS;
  float* dan = dap + NROWS;
  float* out = (float*)d_out;

  hipLaunchKernelGGL(norm_kernel, dim3(NROWS), dim3(256), 0, stream,
                     inputs, l2q, recip, dap, dan);
  hipLaunchKernelGGL(gemm_reduce_kernel, dim3(NTB * NTB), dim3(256), 0, stream,
                     l2q, targets, recip, dap, dan);
  hipLaunchKernelGGL(loss_kernel, dim3(1), dim3(256), 0, stream, dap, dan, out);
}

// Round 20
// 64.153 us; speedup vs baseline: 1.3395x; 1.0722x over previous
//
#include <hip/hip_runtime.h>
#include <hip/hip_bf16.h>
#include <stdint.h>

#define NROWS 4096
#define DIMS  2048
#define BM    128             // tile 128x128
#define BKB   128             // K-tile = 128 int8 = 128 B rows
#define NTILES (DIMS / BKB)   // 16
#define NTB   (NROWS / BM)    // 32 -> 1024 blocks
#define MARGIN_F 0.3f

typedef __attribute__((ext_vector_type(4))) int   i32x4;
typedef __attribute__((ext_vector_type(4))) float f32x4;

__device__ inline void atomicMaxF(float* addr, float v) {
  if (v >= 0.f) atomicMax((int*)addr, __float_as_int(v));
  else          atomicMin((unsigned int*)addr, __float_as_uint(v));
}
__device__ inline void atomicMinF(float* addr, float v) {
  if (v >= 0.f) atomicMin((int*)addr, __float_as_int(v));
  else          atomicMax((unsigned int*)addr, __float_as_uint(v));
}

__device__ inline void load_lds16(const void* g, void* l) {
  __builtin_amdgcn_global_load_lds(
      (const __attribute__((address_space(1))) void*)(g),
      (__attribute__((address_space(3))) void*)(l), 16, 0, 0);
}

// ------- normalize + per-row int8 quantization (q = rint(x*127/amax)) -------
__global__ __launch_bounds__(256) void norm_kernel(const float* __restrict__ in,
                                                   char* __restrict__ l2q,
                                                   float* __restrict__ recip,
                                                   float* __restrict__ dap,
                                                   float* __restrict__ dan) {
  int row = blockIdx.x;
  int t = threadIdx.x;
  const float4* rin = (const float4*)(in + (size_t)row * DIMS);
  float4 v0 = rin[t];
  float4 v1 = rin[t + 256];
  float ss = v0.x*v0.x + v0.y*v0.y + v0.z*v0.z + v0.w*v0.w
           + v1.x*v1.x + v1.y*v1.y + v1.z*v1.z + v1.w*v1.w;
  float am = fmaxf(fmaxf(fmaxf(fabsf(v0.x), fabsf(v0.y)), fmaxf(fabsf(v0.z), fabsf(v0.w))),
                   fmaxf(fmaxf(fabsf(v1.x), fabsf(v1.y)), fmaxf(fabsf(v1.z), fabsf(v1.w))));
  #pragma unroll
  for (int s = 1; s < 64; s <<= 1) {
    ss += __shfl_xor(ss, s);
    am = fmaxf(am, __shfl_xor(am, s));
  }
  __shared__ float wsum[4], wmax[4];
  if ((t & 63) == 0) { wsum[t >> 6] = ss; wmax[t >> 6] = am; }
  __syncthreads();
  float tot = wsum[0] + wsum[1] + wsum[2] + wsum[3];
  float amax = fmaxf(fmaxf(wmax[0], wmax[1]), fmaxf(wmax[2], wmax[3]));
  float rn = 1.0f / sqrtf(tot);
  float qs = 127.0f / amax;
  int q0 = (int)rintf(v0.x * qs), q1 = (int)rintf(v0.y * qs);
  int q2 = (int)rintf(v0.z * qs), q3 = (int)rintf(v0.w * qs);
  int q4 = (int)rintf(v1.x * qs), q5 = (int)rintf(v1.y * qs);
  int q6 = (int)rintf(v1.z * qs), q7 = (int)rintf(v1.w * qs);
  int p0 = (q0 & 255) | ((q1 & 255) << 8) | ((q2 & 255) << 16) | (q3 << 24);
  int p1 = (q4 & 255) | ((q5 & 255) << 8) | ((q6 & 255) << 16) | (q7 << 24);
  int* orow = (int*)(l2q + (size_t)row * DIMS);
  orow[t] = p0;
  orow[t + 256] = p1;
  if (t == 0) {
    recip[row] = amax * rn / 127.0f;
    dap[row] = -__builtin_inff();
    dan[row] = __builtin_inff();
  }
}

// ---------------- fused int8 GEMM (acc = Q . Q^T) + masked row max/min ----------------
// r17 winning skeleton (128x128 tile, 4 waves 2x2 of 64x64,
// mfma_i32_16x16x64_i8, 4 blocks/CU, single-buffer, plain 2-sync loop) with
// ONE isolated change: BK = 128 B (16 K-tiles instead of 32), halving the
// number of per-tile {sync + stage-issue + drain} chain exposures.
// LDS 32 KB single buffer (A [128][128B] 16K + B 16K); 4 blocks/CU = 128 KB.
// Swizzle (128B rows = exact bank wrap): slot c of a row holds data chunk
// q = c ^ (row&7). Staging: inst j covers rows j*32+(tid>>3), slot tid&7,
// source chunk qq = (tid&7)^((tid>>3)&7) -- coalesced 128 B per 8 threads.
// Read: lane (laneq,g), ks-half: slot = (ks*4+g) ^ (laneq&7) -> lanes 0-7
// of a quarter cover all 8 slots (all 32 banks), lanes 8-15 repeat = 2-way
// free. 16 ds_read_b128 + 32 MFMA per wave per tile.
__global__ __launch_bounds__(256, 4) void gemm_reduce_kernel(
    const char* __restrict__ l2q, const int* __restrict__ tgt,
    const float* __restrict__ recip,
    float* __restrict__ dap, float* __restrict__ dan) {
  __shared__ __attribute__((aligned(16))) char ldsbuf[32768];  // A 16K + B 16K

  // XCD-chunked bijective swizzle (1024 blocks, 8 XCDs -> 128 contiguous per XCD)
  int c = blockIdx.x;
  int swz = (c & 7) * 128 + (c >> 3);
  int bi = swz >> 5, bj = swz & 31;

  int tid = threadIdx.x;
  int lane = tid & 63, w = tid >> 6;
  int wr = w >> 1;        // 0..1  (M half: 64 rows)
  int nc = w & 1;         // 0..1  (N half: 64 cols)
  int laneq = lane & 15, g = lane >> 4;

  i32x4 acc[4][4];
  #pragma unroll
  for (int m = 0; m < 4; m++)
    #pragma unroll
    for (int n = 0; n < 4; n++) acc[m][n] = (i32x4){0, 0, 0, 0};

  // --- staging source: inst j covers row j*32 + (tid>>3), slot c = tid&7,
  //     data chunk qq = (tid&7) ^ ((tid>>3)&7)  (row&7 == (tid>>3)&7, since
  //     j*32 % 8 == 0); 8 consecutive threads = one full 128 B row segment ---
  int srow = tid >> 3;                               // 0..31
  int qq = (tid & 7) ^ ((tid >> 3) & 7);
  const char* gA = l2q + ((size_t)(bi * BM + srow)) * DIMS + qq * 16;
  const char* gB = l2q + ((size_t)(bj * BM + srow)) * DIMS + qq * 16;

  // --- fragment read offsets: slot(ks) = ((ks*4+g) ^ (laneq&7))*16 ---
  int slot0 = ((g) ^ (laneq & 7)) * 16;
  int slot1 = ((4 + g) ^ (laneq & 7)) * 16;
  int rowbA = (wr * 64 + laneq) * 128;               // + m*2048
  int rowbB = 16384 + (nc * 64 + laneq) * 128;       // + n*2048

  i32x4 aU[4], bR[4];

  #define STAGE(T)                                                            \
    do {                                                                      \
      _Pragma("unroll")                                                       \
      for (int j = 0; j < 4; ++j) {                                           \
        load_lds16(gA + (size_t)(j * 32) * DIMS + (size_t)(T) * BKB,          \
                   &ldsbuf[j * 4096 + w * 1024]);                             \
        load_lds16(gB + (size_t)(j * 32) * DIMS + (size_t)(T) * BKB,          \
                   &ldsbuf[16384 + j * 4096 + w * 1024]);                     \
      }                                                                       \
    } while (0)

  #define COMPUTE_KS(SLOT)                                                    \
    do {                                                                      \
      _Pragma("unroll")                                                       \
      for (int n = 0; n < 4; n++)                                             \
        bR[n] = *(const i32x4*)&ldsbuf[rowbB + n * 2048 + (SLOT)];            \
      _Pragma("unroll")                                                       \
      for (int m = 0; m < 4; m++)                                             \
        aU[m] = *(const i32x4*)&ldsbuf[rowbA + m * 2048 + (SLOT)];            \
      _Pragma("unroll")                                                       \
      for (int m = 0; m < 4; m++)                                             \
        _Pragma("unroll")                                                     \
        for (int n = 0; n < 4; n++)                                           \
          acc[m][n] = __builtin_amdgcn_mfma_i32_16x16x64_i8(aU[m], bR[n],     \
                                                            acc[m][n], 0, 0, 0); \
    } while (0)

  #pragma unroll 1
  for (int kt = 0; kt < NTILES; ++kt) {
    __syncthreads();                              // prev tile's reads done
    STAGE(kt);
    __syncthreads();                              // drains vmcnt -> visible
    COMPUTE_KS(slot0);
    COMPUTE_KS(slot1);
  }

  // ---- fused masked reduction (r17-identical, verified) ----
  // acc[m][n][r] = Gq[bi*128 + wr*64 + m*16 + g*4 + r]
  //                  [bj*128 + nc*64 + n*16 + laneq]
  int tcol[4];
  float tcr[4];
  #pragma unroll
  for (int n = 0; n < 4; n++) {
    int idx = bj * BM + nc * 64 + n * 16 + laneq;
    tcol[n] = tgt[idx];
    tcr[n] = recip[idx];
  }
  int rbase = bi * BM + wr * 64 + g * 4;

  #pragma unroll
  for (int m = 0; m < 4; m++) {
    #pragma unroll
    for (int r = 0; r < 4; r++) {
      int grow = rbase + m * 16 + r;
      int trow = tgt[grow];
      float rrw = recip[grow];
      float ap = -__builtin_inff(), an = __builtin_inff();
      #pragma unroll
      for (int n = 0; n < 4; n++) {
        float d = -(float)acc[m][n][r] * rrw * tcr[n];
        bool same = (trow == tcol[n]);
        ap = same ? fmaxf(ap, d) : ap;
        an = same ? an : fminf(an, d);
      }
      #pragma unroll
      for (int s = 1; s < 16; s <<= 1) {
        ap = fmaxf(ap, __shfl_xor(ap, s));
        an = fminf(an, __shfl_xor(an, s));
      }
      if (laneq == 0) {
        atomicMaxF(&dap[grow], ap);
        atomicMinF(&dan[grow], an);
      }
    }
  }
  #undef STAGE
  #undef COMPUTE_KS
}

// ---------------- final loss ----------------
__global__ __launch_bounds__(256) void loss_kernel(const float* __restrict__ dap,
                                                   const float* __restrict__ dan,
                                                   float* __restrict__ out) {
  int t = threadIdx.x;
  float s = 0.f;
  for (int i = t; i < NROWS; i += 256) {
    float v = dap[i] - dan[i] + MARGIN_F;
    s += v > 0.f ? v : 0.f;
  }
  #pragma unroll
  for (int sh = 1; sh < 64; sh <<= 1) s += __shfl_xor(s, sh);
  __shared__ float ws[4];
  if ((t & 63) == 0) ws[t >> 6] = s;
  __syncthreads();
  if (t == 0) out[0] = (ws[0] + ws[1] + ws[2] + ws[3]) * (1.0f / (float)NROWS);
}

extern "C" void kernel_launch(void* const* d_in, const int* in_sizes, int n_in,
                              void* d_out, int out_size, void* d_ws, size_t ws_size,
                              hipStream_t stream) {
  const float* inputs = (const float*)d_in[0];
  const int* targets = (const int*)d_in[1];
  char* l2q = (char*)d_ws;
  float* recip = (float*)((char*)d_ws + (size_t)NROWS * DIMS);
  float* dap = recip + NROWS;
  float* dan = dap + NROWS;
  float* out = (float*)d_out;

  hipLaunchKernelGGL(norm_kernel, dim3(NROWS), dim3(256), 0, stream,
                     inputs, l2q, recip, dap, dan);
  hipLaunchKernelGGL(gemm_reduce_kernel, dim3(NTB * NTB), dim3(256), 0, stream,
                     l2q, targets, recip, dap, dan);
  hipLaunchKernelGGL(loss_kernel, dim3(1), dim3(256), 0, stream, dap, dan, out);
}

// Round 21
// 52.008 us; speedup vs baseline: 1.6522x; 1.2335x over previous
//
#include <hip/hip_runtime.h>
#include <hip/hip_bf16.h>
#include <stdint.h>

#define NROWS 4096
#define DIMS  2048
#define BM    128             // tile 128x128
#define BKB   128             // K-tile = 128 int8 = 128 B rows
#define NTILES (DIMS / BKB)   // 16
#define NT    (NROWS / BM)    // 32 tile rows
#define NBLK  (NT * (NT + 1) / 2)   // 528 upper-tri blocks
#define MARGIN_F 0.3f

typedef __attribute__((ext_vector_type(4))) int   i32x4;
typedef __attribute__((ext_vector_type(4))) float f32x4;

__device__ inline void atomicMaxF(float* addr, float v) {
  if (v >= 0.f) atomicMax((int*)addr, __float_as_int(v));
  else          atomicMin((unsigned int*)addr, __float_as_uint(v));
}
__device__ inline void atomicMinF(float* addr, float v) {
  if (v >= 0.f) atomicMin((int*)addr, __float_as_int(v));
  else          atomicMax((unsigned int*)addr, __float_as_uint(v));
}

__device__ inline void load_lds16(const void* g, void* l) {
  __builtin_amdgcn_global_load_lds(
      (const __attribute__((address_space(1))) void*)(g),
      (__attribute__((address_space(3))) void*)(l), 16, 0, 0);
}

// ------- normalize + per-row int8 quantization (q = rint(x*127/amax)) -------
__global__ __launch_bounds__(256) void norm_kernel(const float* __restrict__ in,
                                                   char* __restrict__ l2q,
                                                   float* __restrict__ recip,
                                                   float* __restrict__ dap,
                                                   float* __restrict__ dan) {
  int row = blockIdx.x;
  int t = threadIdx.x;
  const float4* rin = (const float4*)(in + (size_t)row * DIMS);
  float4 v0 = rin[t];
  float4 v1 = rin[t + 256];
  float ss = v0.x*v0.x + v0.y*v0.y + v0.z*v0.z + v0.w*v0.w
           + v1.x*v1.x + v1.y*v1.y + v1.z*v1.z + v1.w*v1.w;
  float am = fmaxf(fmaxf(fmaxf(fabsf(v0.x), fabsf(v0.y)), fmaxf(fabsf(v0.z), fabsf(v0.w))),
                   fmaxf(fmaxf(fabsf(v1.x), fabsf(v1.y)), fmaxf(fabsf(v1.z), fabsf(v1.w))));
  #pragma unroll
  for (int s = 1; s < 64; s <<= 1) {
    ss += __shfl_xor(ss, s);
    am = fmaxf(am, __shfl_xor(am, s));
  }
  __shared__ float wsum[4], wmax[4];
  if ((t & 63) == 0) { wsum[t >> 6] = ss; wmax[t >> 6] = am; }
  __syncthreads();
  float tot = wsum[0] + wsum[1] + wsum[2] + wsum[3];
  float amax = fmaxf(fmaxf(wmax[0], wmax[1]), fmaxf(wmax[2], wmax[3]));
  float rn = 1.0f / sqrtf(tot);
  float qs = 127.0f / amax;
  int q0 = (int)rintf(v0.x * qs), q1 = (int)rintf(v0.y * qs);
  int q2 = (int)rintf(v0.z * qs), q3 = (int)rintf(v0.w * qs);
  int q4 = (int)rintf(v1.x * qs), q5 = (int)rintf(v1.y * qs);
  int q6 = (int)rintf(v1.z * qs), q7 = (int)rintf(v1.w * qs);
  int p0 = (q0 & 255) | ((q1 & 255) << 8) | ((q2 & 255) << 16) | (q3 << 24);
  int p1 = (q4 & 255) | ((q5 & 255) << 8) | ((q6 & 255) << 16) | (q7 << 24);
  int* orow = (int*)(l2q + (size_t)row * DIMS);
  orow[t] = p0;
  orow[t + 256] = p1;
  if (t == 0) {
    recip[row] = amax * rn / 127.0f;
    dap[row] = -__builtin_inff();
    dan[row] = __builtin_inff();
  }
}

// ---------------- fused symmetric int8 GEMM + masked row/col max/min ----------------
// r20 winning kernel (128x128 tile, 4 waves, BK=128, single-buffer 32 KB,
// plain 2-sync loop, mfma_i32_16x16x64_i8, verified swizzles) with ONE
// change: UPPER-TRIANGULAR grid (bi<=bj, 528 blocks instead of 1024 --
// halves the GEMM work now that the structure is throughput-scaled, r20
// evidence) + the r13-verified transposed-contribution epilogue for
// off-diagonal blocks (per-column max/min -> rows of the bj panel;
// atomics idempotent, so diag blocks just skip it).
__global__ __launch_bounds__(256, 4) void gemm_reduce_kernel(
    const char* __restrict__ l2q, const int* __restrict__ tgt,
    const float* __restrict__ recip,
    float* __restrict__ dap, float* __restrict__ dan) {
  __shared__ __attribute__((aligned(16))) char ldsbuf[32768];  // A 16K + B 16K

  // XCD-chunked bijective swizzle (528 = 8 x 66), then upper-tri decode
  int c = blockIdx.x;
  int swz = (c & 7) * 66 + (c >> 3);
  int bi = 0, rem = swz;
  #pragma unroll 1
  while (rem >= NT - bi) { rem -= NT - bi; ++bi; }
  int bj = bi + rem;
  bool offd = (bi != bj);

  int tid = threadIdx.x;
  int lane = tid & 63, w = tid >> 6;
  int wr = w >> 1;        // 0..1  (M half: 64 rows)
  int nc = w & 1;         // 0..1  (N half: 64 cols)
  int laneq = lane & 15, g = lane >> 4;

  i32x4 acc[4][4];
  #pragma unroll
  for (int m = 0; m < 4; m++)
    #pragma unroll
    for (int n = 0; n < 4; n++) acc[m][n] = (i32x4){0, 0, 0, 0};

  // --- staging source (r20-identical): inst j covers row j*32 + (tid>>3),
  //     slot c = tid&7, data chunk qq = (tid&7) ^ ((tid>>3)&7); coalesced
  //     128 B per 8 threads ---
  int srow = tid >> 3;                               // 0..31
  int qq = (tid & 7) ^ ((tid >> 3) & 7);
  const char* gA = l2q + ((size_t)(bi * BM + srow)) * DIMS + qq * 16;
  const char* gB = l2q + ((size_t)(bj * BM + srow)) * DIMS + qq * 16;

  // --- fragment read offsets (r20-identical; 0 conflicts) ---
  int slot0 = ((g) ^ (laneq & 7)) * 16;
  int slot1 = ((4 + g) ^ (laneq & 7)) * 16;
  int rowbA = (wr * 64 + laneq) * 128;               // + m*2048
  int rowbB = 16384 + (nc * 64 + laneq) * 128;       // + n*2048

  i32x4 aU[4], bR[4];

  #define STAGE(T)                                                            \
    do {                                                                      \
      _Pragma("unroll")                                                       \
      for (int j = 0; j < 4; ++j) {                                           \
        load_lds16(gA + (size_t)(j * 32) * DIMS + (size_t)(T) * BKB,          \
                   &ldsbuf[j * 4096 + w * 1024]);                             \
        load_lds16(gB + (size_t)(j * 32) * DIMS + (size_t)(T) * BKB,          \
                   &ldsbuf[16384 + j * 4096 + w * 1024]);                     \
      }                                                                       \
    } while (0)

  #define COMPUTE_KS(SLOT)                                                    \
    do {                                                                      \
      _Pragma("unroll")                                                       \
      for (int n = 0; n < 4; n++)                                             \
        bR[n] = *(const i32x4*)&ldsbuf[rowbB + n * 2048 + (SLOT)];            \
      _Pragma("unroll")                                                       \
      for (int m = 0; m < 4; m++)                                             \
        aU[m] = *(const i32x4*)&ldsbuf[rowbA + m * 2048 + (SLOT)];            \
      _Pragma("unroll")                                                       \
      for (int m = 0; m < 4; m++)                                             \
        _Pragma("unroll")                                                     \
        for (int n = 0; n < 4; n++)                                           \
          acc[m][n] = __builtin_amdgcn_mfma_i32_16x16x64_i8(aU[m], bR[n],     \
                                                            acc[m][n], 0, 0, 0); \
    } while (0)

  #pragma unroll 1
  for (int kt = 0; kt < NTILES; ++kt) {
    __syncthreads();                              // prev tile's reads done
    STAGE(kt);
    __syncthreads();                              // drains vmcnt -> visible
    COMPUTE_KS(slot0);
    COMPUTE_KS(slot1);
  }

  // ---- fused masked reduction ----
  // acc[m][n][r] = Gq[bi*128 + wr*64 + m*16 + g*4 + r]
  //                  [bj*128 + nc*64 + n*16 + laneq]
  int tcol[4];
  float tcr[4];
  #pragma unroll
  for (int n = 0; n < 4; n++) {
    int idx = bj * BM + nc * 64 + n * 16 + laneq;
    tcol[n] = tgt[idx];
    tcr[n] = recip[idx];
  }
  int rbase = bi * BM + wr * 64 + g * 4;

  float apc[4], anc[4];   // per-column partials (transposed contribution)
  #pragma unroll
  for (int n = 0; n < 4; n++) { apc[n] = -__builtin_inff(); anc[n] = __builtin_inff(); }

  #pragma unroll
  for (int m = 0; m < 4; m++) {
    #pragma unroll
    for (int r = 0; r < 4; r++) {
      int grow = rbase + m * 16 + r;
      int trow = tgt[grow];
      float rrw = recip[grow];
      float ap = -__builtin_inff(), an = __builtin_inff();
      #pragma unroll
      for (int n = 0; n < 4; n++) {
        float d = -(float)acc[m][n][r] * rrw * tcr[n];
        bool same = (trow == tcol[n]);
        ap = same ? fmaxf(ap, d) : ap;
        an = same ? an : fminf(an, d);
        apc[n] = same ? fmaxf(apc[n], d) : apc[n];
        anc[n] = same ? anc[n] : fminf(anc[n], d);
      }
      #pragma unroll
      for (int s = 1; s < 16; s <<= 1) {
        ap = fmaxf(ap, __shfl_xor(ap, s));
        an = fminf(an, __shfl_xor(an, s));
      }
      if (laneq == 0) {
        atomicMaxF(&dap[grow], ap);
        atomicMinF(&dan[grow], an);
      }
    }
  }

  if (offd) {
    // transposed contribution: per-column max/min -> rows of the bj panel.
    // combine across the 4 lanes sharing a column (g differs: xor 16, 32).
    #pragma unroll
    for (int n = 0; n < 4; n++) {
      float ap = apc[n], an = anc[n];
      ap = fmaxf(ap, __shfl_xor(ap, 16));
      ap = fmaxf(ap, __shfl_xor(ap, 32));
      an = fminf(an, __shfl_xor(an, 16));
      an = fminf(an, __shfl_xor(an, 32));
      if (g == 0) {
        int gcol = bj * BM + nc * 64 + n * 16 + laneq;
        atomicMaxF(&dap[gcol], ap);
        atomicMinF(&dan[gcol], an);
      }
    }
  }
  #undef STAGE
  #undef COMPUTE_KS
}

// ---------------- final loss ----------------
__global__ __launch_bounds__(256) void loss_kernel(const float* __restrict__ dap,
                                                   const float* __restrict__ dan,
                                                   float* __restrict__ out) {
  int t = threadIdx.x;
  float s = 0.f;
  for (int i = t; i < NROWS; i += 256) {
    float v = dap[i] - dan[i] + MARGIN_F;
    s += v > 0.f ? v : 0.f;
  }
  #pragma unroll
  for (int sh = 1; sh < 64; sh <<= 1) s += __shfl_xor(s, sh);
  __shared__ float ws[4];
  if ((t & 63) == 0) ws[t >> 6] = s;
  __syncthreads();
  if (t == 0) out[0] = (ws[0] + ws[1] + ws[2] + ws[3]) * (1.0f / (float)NROWS);
}

extern "C" void kernel_launch(void* const* d_in, const int* in_sizes, int n_in,
                              void* d_out, int out_size, void* d_ws, size_t ws_size,
                              hipStream_t stream) {
  const float* inputs = (const float*)d_in[0];
  const int* targets = (const int*)d_in[1];
  char* l2q = (char*)d_ws;
  float* recip = (float*)((char*)d_ws + (size_t)NROWS * DIMS);
  float* dap = recip + NROWS;
  float* dan = dap + NROWS;
  float* out = (float*)d_out;

  hipLaunchKernelGGL(norm_kernel, dim3(NROWS), dim3(256), 0, stream,
                     inputs, l2q, recip, dap, dan);
  hipLaunchKernelGGL(gemm_reduce_kernel, dim3(NBLK), dim3(256), 0, stream,
                     l2q, targets, recip, dap, dan);
  hipLaunchKernelGGL(loss_kernel, dim3(1), dim3(256), 0, stream, dap, dan, out);
}